// Round 4
// baseline (135.894 us; speedup 1.0000x reference)
//
#include <hip/hip_runtime.h>

#define D 128
#define NT2 2080            // 64*65/2 upper-triangular 128x128 super-tiles

typedef __attribute__((ext_vector_type(8))) short short8;   // 8 x bf16 (4 VGPRs)
typedef __attribute__((ext_vector_type(4))) float float4v;  // 4 x f32 acc
typedef __attribute__((ext_vector_type(2))) float float2v;  // 2 x f32 (v_pk_* ops)

static __device__ __forceinline__ unsigned short f2bf(float f) {
    unsigned int u = __float_as_uint(f);
    unsigned int r = (u + 0x7fffu + ((u >> 16) & 1u)) >> 16;  // RNE
    return (unsigned short)r;
}

// async global->LDS, 16B per lane; lds dest must be wave-uniform base + lane*16
static __device__ __forceinline__ void gld16(const void* g, void* l) {
    __builtin_amdgcn_global_load_lds(
        (const __attribute__((address_space(1))) unsigned int*)g,
        (__attribute__((address_space(3))) unsigned int*)l, 16, 0, 0);
}

// ws float-index layout:
//   [0]              ticket (uint)        ZEROED by memset node
//   [8..40)          ss32[32] (f32)       ZEROED; k_prep atomicAdd rowsq block-sums
//   [64..192)        colsum[128] (f32)    ZEROED; k_prep atomicAdd column sums
//   [192..256)       acc32[32] (f64)      ZEROED; mmd_main per-block partials
//   [33280..41471]   rowsq[8192]          k_prep plain stores
//   [65536..589824)  XT: bf16 X, FRAGMENT-MAJOR tiled (2 MB)
//                    8-bf16 chunk c of row r -> uint4 idx (r>>4)*256 + c*16 + (r&15)
//                    => 128-row super-panel p is 32KB contiguous at uint4 idx p*2048

// ---- P1+P2 fused in one dispatch (independent grid sections, both read only X):
//      blocks [0,2048): rowsq + tiled bf16 convert, one wave per row;
//                       block-sum of 4 rowsq -> atomicAdd into ss32[b&31]
//      blocks [2048,2176): block-partial column sums -> atomicAdd into colsum[128]
__global__ __launch_bounds__(256) void k_prep(const float* __restrict__ src,
                                              const float* __restrict__ tgt,
                                              float* __restrict__ wsf,
                                              unsigned int* __restrict__ XTu) {
    __shared__ float shs[4];
    __shared__ float cp[2][128];
    if (blockIdx.x < 2048) {
        float* rowsq = wsf + 33280;
        const int wv = threadIdx.x >> 6, lane = threadIdx.x & 63;
        const int gr = blockIdx.x * 4 + wv;
        const float* Xr = (gr < 4096) ? src + (size_t)gr * D : tgt + (size_t)(gr - 4096) * D;
        float2 f = ((const float2*)Xr)[lane];
        // tiled store: uint index (r>>4)*1024 + c*64 + (r&15)*4 + (lane&3), c = lane>>2
        XTu[(gr >> 4) * 1024 + (lane >> 2) * 64 + (gr & 15) * 4 + (lane & 3)] =
            (unsigned)f2bf(f.x) | ((unsigned)f2bf(f.y) << 16);
        float s = f.x * f.x + f.y * f.y;
        #pragma unroll
        for (int off = 32; off; off >>= 1) s += __shfl_down(s, off);
        if (lane == 0) { rowsq[gr] = s; shs[wv] = s; }
        __syncthreads();
        if (threadIdx.x == 0)
            atomicAdd(wsf + 8 + (blockIdx.x & 31), (shs[0] + shs[1]) + (shs[2] + shs[3]));
    } else {
        int b = blockIdx.x - 2048;
        int col = threadIdx.x & 127, half = threadIdx.x >> 7;
        const float* X = (b < 64) ? src + (size_t)(b * 64) * D
                                  : tgt + (size_t)((b - 64) * 64) * D;
        float p0 = 0.f, p1 = 0.f, p2 = 0.f, p3 = 0.f;   // independent chains
        #pragma unroll 4
        for (int i = 0; i < 32; i += 4) {
            p0 += X[(size_t)(2 * (i + 0) + half) * D + col];
            p1 += X[(size_t)(2 * (i + 1) + half) * D + col];
            p2 += X[(size_t)(2 * (i + 2) + half) * D + col];
            p3 += X[(size_t)(2 * (i + 3) + half) * D + col];
        }
        cp[half][col] = (p0 + p1) + (p2 + p3);
        __syncthreads();
        if (threadIdx.x < 128)
            atomicAdd(wsf + 64 + threadIdx.x, cp[0][threadIdx.x] + cp[1][threadIdx.x]);
    }
}

// ---- M: one 128x128 super-tile per 4-wave block (round-2 proven structure).
//      Prologue: every wave redundantly computes c4 from ss32/colsum (~130 loads).
//      Tail: per-block f64 partial -> slot atomicAdd; vmcnt(0); ticket atomic;
//      winner reduces 32 slots (coherence-point reads) and writes out. ----
__global__ __launch_bounds__(256) void mmd_main(const uint4* __restrict__ XT,
                                                float* __restrict__ wsf,
                                                float* __restrict__ out) {
    __shared__ uint4 lds[4096];   // 64 KB: A panel [0,2048), B panel [2048,4096)
    __shared__ float fpart[4];
    __shared__ int lastflag;
    const float* rowsq = wsf + 33280;
    const int tid = threadIdx.x;
    const int lane = tid & 63, wv = tid >> 6;
    const int quad = lane >> 4, mrow = lane & 15;
    const int wm = wv >> 1, wn = wv & 1;             // quadrant of the super-tile

    // ---- per-wave redundant c4 (no LDS, no barrier; inputs L2-resident) ----
    float c4;
    {
        const float* colsum = wsf + 64;
        const float* ss32 = wsf + 8;
        float cA = colsum[lane], cB = colsum[64 + lane];
        float sq = cA * cA + cB * cB;                // -> sum of colsum^2
        float sv = (lane < 32) ? ss32[lane] : 0.f;   // -> sum of rowsq
        #pragma unroll
        for (int off = 32; off; off >>= 1) {
            sq += __shfl_down(sq, off);
            sv += __shfl_down(sv, off);
        }
        double sumL2 = 2.0 * 8192.0 * (double)sv - 2.0 * (double)sq;
        double bw = sumL2 / (8192.0 * 8192.0 - 8192.0) / 4.0;   // /KERNEL_MUL^(5/2)
        float c4l = (float)(-1.4426950408889634 / (bw * 16.0));
        c4 = __shfl(c4l, 0);                         // lane 0 has the valid value
    }

    // XCD-aware swizzle (2080 % 8 == 0 -> bijective): contiguous t2 chunk per XCD
    int b = blockIdx.x;
    int t2 = (b & 7) * (NT2 / 8) + (b >> 3);

    // t2 -> (pi <= pj) over 64 super-panels; base(p) = p*(129-p)/2
    int pi = (int)((129.0 - sqrt(129.0 * 129.0 - 8.0 * (double)t2)) * 0.5);
    auto base = [](int p) { return (p * (129 - p)) >> 1; };
    while (base(pi + 1) <= t2) ++pi;
    while (base(pi) > t2) --pi;
    int pj = pi + (t2 - base(pi));

    // stage panel(s): 32KB contiguous each; 256 thr x 16B = 4KB per issue
    const char* gA = (const char*)(XT + (size_t)pi * 2048);
    char* lb = (char*)lds;
    #pragma unroll
    for (int it = 0; it < 8; ++it)
        gld16(gA + it * 4096 + tid * 16, lb + it * 4096 + tid * 16);
    if (pj != pi) {
        const char* gB = (const char*)(XT + (size_t)pj * 2048);
        #pragma unroll
        for (int it = 0; it < 8; ++it)
            gld16(gB + it * 4096 + tid * 16, lb + 32768 + it * 4096 + tid * 16);
    }
    const uint4* As = lds + wm * 1024;                               // 64-row half
    const uint4* Bs = ((pj != pi) ? lds + 2048 : lds) + wn * 1024;
    const int ti = pi * 2 + wm, tj = pj * 2 + wn;                    // 64-row tiles
    __syncthreads();   // drains vmcnt (global_load_lds) before ds_reads

    float4v acc[4][4];
    #pragma unroll
    for (int mt = 0; mt < 4; ++mt)
        #pragma unroll
        for (int nt = 0; nt < 4; ++nt)
            acc[mt][nt] = (float4v){0.f, 0.f, 0.f, 0.f};

    #pragma unroll
    for (int kc = 0; kc < 4; ++kc) {
        short8 af[4], bf[4];
        #pragma unroll
        for (int mt = 0; mt < 4; ++mt)
            af[mt] = *(const short8*)&As[mt * 256 + kc * 64 + lane];
        #pragma unroll
        for (int nt = 0; nt < 4; ++nt)
            bf[nt] = *(const short8*)&Bs[nt * 256 + kc * 64 + lane];
        #pragma unroll
        for (int mt = 0; mt < 4; ++mt)
            #pragma unroll
            for (int nt = 0; nt < 4; ++nt)
                acc[mt][nt] = __builtin_amdgcn_mfma_f32_16x16x32_bf16(af[mt], bf[nt], acc[mt][nt], 0, 0, 0);
    }

    // epilogue: e = exp2(pk_fma(d, -2c4, rA*c4 + rB*c4)); sum e^{1,2,4,8,16}
    const float* rsqA = rowsq + ti * 64;
    const float* rsqB = rowsq + tj * 64;
    const float cm2 = -2.f * c4;
    const float2v cm2v = {cm2, cm2};
    float2v part2 = {0.f, 0.f};
    #pragma unroll
    for (int mt = 0; mt < 4; ++mt) {
        const float2v rA01 = { rsqA[mt * 16 + quad * 4 + 0] * c4,
                               rsqA[mt * 16 + quad * 4 + 1] * c4 };
        const float2v rA23 = { rsqA[mt * 16 + quad * 4 + 2] * c4,
                               rsqA[mt * 16 + quad * 4 + 3] * c4 };
        #pragma unroll
        for (int nt = 0; nt < 4; ++nt) {
            float rBc = rsqB[nt * 16 + mrow] * c4;
            const float2v rB2 = {rBc, rBc};
            float4v d = acc[mt][nt];
            float2v d01 = {d[0], d[1]}, d23 = {d[2], d[3]};
            float2v a01 = d01 * cm2v + (rA01 + rB2);   // v_pk_fma + v_pk_add
            float2v a23 = d23 * cm2v + (rA23 + rB2);
            float2v e1a = { __builtin_amdgcn_exp2f(a01[0]), __builtin_amdgcn_exp2f(a01[1]) };
            float2v e1b = { __builtin_amdgcn_exp2f(a23[0]), __builtin_amdgcn_exp2f(a23[1]) };
            float2v e2a = e1a * e1a, e4a = e2a * e2a, e8a = e4a * e4a, e16a = e8a * e8a;
            float2v e2b = e1b * e1b, e4b = e2b * e2b, e8b = e4b * e4b, e16b = e8b * e8b;
            part2 += (e1a + e2a) + ((e4a + e8a) + e16a);
            part2 += (e1b + e2b) + ((e4b + e8b) + e16b);
        }
    }
    float part = part2[0] + part2[1];
    #pragma unroll
    for (int off = 32; off; off >>= 1) part += __shfl_down(part, off);

    if (lane == 0) {
        float wgt;
        if (pi == pj) {
            if (wm == 1 && wn == 0) wgt = 0.f;        // duplicate quadrant
            else wgt = (ti == tj) ? 1.f : 2.f;
        } else {
            wgt = ((pi < 32) == (pj < 32)) ? 2.f : -2.f;
        }
        fpart[wv] = wgt * part;
    }
    __syncthreads();
    if (tid == 0) {
        double bs = ((double)fpart[0] + fpart[1]) + ((double)fpart[2] + fpart[3]);
        double* accd = (double*)(wsf + 192);
        atomicAdd(accd + (b & 31), bs);               // relaxed agent-scope atomic
        asm volatile("s_waitcnt vmcnt(0)" ::: "memory");   // slot-add before ticket
        unsigned int old = atomicAdd((unsigned int*)wsf, 1u);
        lastflag = (old == NT2 - 1) ? 1 : 0;
    }
    __syncthreads();
    if (lastflag && wv == 0) {                        // winner: fused final reduce
        double* accd = (double*)(wsf + 192);
        double v = (lane < 32) ? atomicAdd(accd + lane, 0.0) : 0.0;  // coherent reads
        #pragma unroll
        for (int off = 32; off; off >>= 1) v += __shfl_down(v, off);
        if (lane == 0) out[0] = (float)(v * (1.0 / (4096.0 * 4096.0)));
    }
}

extern "C" void kernel_launch(void* const* d_in, const int* in_sizes, int n_in,
                              void* d_out, int out_size, void* d_ws, size_t ws_size,
                              hipStream_t stream) {
    const float* src = (const float*)d_in[0];
    const float* tgt = (const float*)d_in[1];
    float* wsf = (float*)d_ws;
    unsigned int* XTu = (unsigned int*)(wsf + 65536);   // byte 256K, 2 MB tiled bf16

    hipMemsetAsync(wsf, 0, 1024, stream);   // ticket + ss32 + colsum + acc32
    hipLaunchKernelGGL(k_prep, dim3(2176), dim3(256), 0, stream, src, tgt, wsf, XTu);
    hipLaunchKernelGGL(mmd_main, dim3(NT2), dim3(256), 0, stream,
                       (const uint4*)XTu, wsf, (float*)d_out);
}

// Round 5
// 102.306 us; speedup vs baseline: 1.3283x; 1.3283x over previous
//
#include <hip/hip_runtime.h>

#define D 128
#define NT2 2080            // 64*65/2 upper-triangular 128x128 super-panel pairs
#define MBLK 256            // persistent blocks, 1 per CU (96 KB LDS each)

typedef __attribute__((ext_vector_type(8))) short short8;   // 8 x bf16 (4 VGPRs)
typedef __attribute__((ext_vector_type(4))) float float4v;  // 4 x f32 acc
typedef __attribute__((ext_vector_type(2))) float float2v;  // 2 x f32 (v_pk_* ops)

static __device__ __forceinline__ unsigned short f2bf(float f) {
    unsigned int u = __float_as_uint(f);
    unsigned int r = (u + 0x7fffu + ((u >> 16) & 1u)) >> 16;  // RNE
    return (unsigned short)r;
}

// async global->LDS, 16B per lane; lds dest must be wave-uniform base + lane*16
static __device__ __forceinline__ void gld16(const void* g, void* l) {
    __builtin_amdgcn_global_load_lds(
        (const __attribute__((address_space(1))) unsigned int*)g,
        (__attribute__((address_space(3))) unsigned int*)l, 16, 0, 0);
}

// ws float-index layout:
//   [0]              (unused)             ZEROED by memset node
//   [8..40)          ss32[32] (f32)       ZEROED; k_prep atomicAdd rowsq block-sums
//   [64..192)        colsum[128] (f32)    ZEROED; k_prep atomicAdd column sums
//   [192..256)       acc32[32] (f64)      ZEROED; mmd_main per-block partials (8 adds/slot)
//   [33280..41471]   rowsq[8192]          k_prep plain stores
//   [65536..589824)  XT: bf16 X, FRAGMENT-MAJOR tiled (2 MB)
//                    8-bf16 chunk c of row r -> uint4 idx (r>>4)*256 + c*16 + (r&15)
//                    => 128-row super-panel p is 32KB contiguous at uint4 idx p*2048

// ---- P1+P2 fused (proven round-4 version, unchanged) ----
__global__ __launch_bounds__(256) void k_prep(const float* __restrict__ src,
                                              const float* __restrict__ tgt,
                                              float* __restrict__ wsf,
                                              unsigned int* __restrict__ XTu) {
    __shared__ float shs[4];
    __shared__ float cp[2][128];
    if (blockIdx.x < 2048) {
        float* rowsq = wsf + 33280;
        const int wv = threadIdx.x >> 6, lane = threadIdx.x & 63;
        const int gr = blockIdx.x * 4 + wv;
        const float* Xr = (gr < 4096) ? src + (size_t)gr * D : tgt + (size_t)(gr - 4096) * D;
        float2 f = ((const float2*)Xr)[lane];
        XTu[(gr >> 4) * 1024 + (lane >> 2) * 64 + (gr & 15) * 4 + (lane & 3)] =
            (unsigned)f2bf(f.x) | ((unsigned)f2bf(f.y) << 16);
        float s = f.x * f.x + f.y * f.y;
        #pragma unroll
        for (int off = 32; off; off >>= 1) s += __shfl_down(s, off);
        if (lane == 0) { rowsq[gr] = s; shs[wv] = s; }
        __syncthreads();
        if (threadIdx.x == 0)
            atomicAdd(wsf + 8 + (blockIdx.x & 31), (shs[0] + shs[1]) + (shs[2] + shs[3]));
    } else {
        int b = blockIdx.x - 2048;
        int col = threadIdx.x & 127, half = threadIdx.x >> 7;
        const float* X = (b < 64) ? src + (size_t)(b * 64) * D
                                  : tgt + (size_t)((b - 64) * 64) * D;
        float p0 = 0.f, p1 = 0.f, p2 = 0.f, p3 = 0.f;
        #pragma unroll 4
        for (int i = 0; i < 32; i += 4) {
            p0 += X[(size_t)(2 * (i + 0) + half) * D + col];
            p1 += X[(size_t)(2 * (i + 1) + half) * D + col];
            p2 += X[(size_t)(2 * (i + 2) + half) * D + col];
            p3 += X[(size_t)(2 * (i + 3) + half) * D + col];
        }
        cp[half][col] = (p0 + p1) + (p2 + p3);
        __syncthreads();
        if (threadIdx.x < 128)
            atomicAdd(wsf + 64 + threadIdx.x, cp[0][threadIdx.x] + cp[1][threadIdx.x]);
    }
}

// ---- M: persistent blocks, A-panel resident + B double-buffer prefetch.
//      256 blocks x 512 thr (8 waves, 64x32 sub-tile each). Per chunk of ~8
//      consecutive t2 (same pi run): stage A once; per tile, prefetch next B
//      during compute. One vmcnt(0)+barrier per tile. Non-returning f64
//      atomicAdd tail (no ticket, no fence). ----
__global__ __launch_bounds__(512, 2) void mmd_main(const uint4* __restrict__ XT,
                                                   float* __restrict__ wsf) {
    __shared__ uint4 Alds[2048];        // 32 KB A panel (per-run resident)
    __shared__ uint4 Blds[2][2048];     // 2 x 32 KB B double-buffer
    __shared__ double dred[8];

    const float* rowsq = wsf + 33280;
    const int tid = threadIdx.x, lane = tid & 63, wv = tid >> 6;
    const int quad = lane >> 4, mrow = lane & 15;
    const int wm = wv >> 2, wn = wv & 3;       // 64-row half, 32-col quarter
    const int b = blockIdx.x;

    // ---- per-wave redundant c4 (3 vector loads + shuffles; L2-resident) ----
    float c4;
    {
        const float* colsum = wsf + 64;
        const float* ss32 = wsf + 8;
        float cA = colsum[lane], cB = colsum[64 + lane];
        float sq = cA * cA + cB * cB;
        float sv = (lane < 32) ? ss32[lane] : 0.f;
        #pragma unroll
        for (int off = 32; off; off >>= 1) {
            sq += __shfl_down(sq, off);
            sv += __shfl_down(sv, off);
        }
        double sumL2 = 2.0 * 8192.0 * (double)sv - 2.0 * (double)sq;
        double bw = sumL2 / (8192.0 * 8192.0 - 8192.0) / 4.0;   // /KERNEL_MUL^(5/2)
        float c4l = (float)(-1.4426950408889634 / (bw * 16.0));
        c4 = __shfl(c4l, 0);
    }
    const float cm2 = -2.f * c4;
    const float2v cm2v = {cm2, cm2};

    // contiguous chunk of tiles for this block: [t, t1)
    int t = (NT2 * b) >> 8;
    const int t1 = (NT2 * (b + 1)) >> 8;
    int pi = (int)((129.0 - sqrt(129.0 * 129.0 - 8.0 * (double)t)) * 0.5);
    while ((((pi + 1) * (129 - (pi + 1))) >> 1) <= t) ++pi;
    while (((pi * (129 - pi)) >> 1) > t) --pi;
    int pj = pi + (t - ((pi * (129 - pi)) >> 1));

    int piA = -1, cur = 0;
    double wacc = 0.0;                  // lane-0 meaningful only
    float rAc[4][4];                    // per-run hoisted rowsqA * c4

    while (t < t1) {
        if (piA != pi) {                // new run: stage A + first B into buf0
            __syncthreads();            // prior readers done (no DMA in flight here)
            const char* gA = (const char*)(XT + (size_t)pi * 2048);
            const char* gB = (const char*)(XT + (size_t)pj * 2048);
            char* lA = (char*)Alds;
            char* lB = (char*)Blds[0];
            #pragma unroll
            for (int it = 0; it < 4; ++it) {
                gld16(gA + it * 8192 + tid * 16, lA + it * 8192 + tid * 16);
                gld16(gB + it * 8192 + tid * 16, lB + it * 8192 + tid * 16);
            }
            #pragma unroll
            for (int mt = 0; mt < 4; ++mt)
                #pragma unroll
                for (int r = 0; r < 4; ++r)
                    rAc[mt][r] = rowsq[pi * 128 + wm * 64 + mt * 16 + quad * 4 + r] * c4;
            cur = 0; piA = pi;
            asm volatile("s_waitcnt vmcnt(0)" ::: "memory");
            __syncthreads();
        } else {                        // prefetched B (issued last iter) arrival
            asm volatile("s_waitcnt vmcnt(0)" ::: "memory");
            __syncthreads();
        }

        // next tile; prefetch its B into the other buffer if same run
        int npj = pj + 1, npi = pi;
        if (npj == 64) { npi = pi + 1; npj = npi; }
        const bool pre = (t + 1 < t1) && (npi == pi);
        if (pre) {
            const char* gB = (const char*)(XT + (size_t)npj * 2048);
            char* lB = (char*)Blds[cur ^ 1];
            #pragma unroll
            for (int it = 0; it < 4; ++it)
                gld16(gB + it * 8192 + tid * 16, lB + it * 8192 + tid * 16);
        }

        float rBc0 = rowsq[pj * 128 + wn * 32 + mrow] * c4;
        float rBc1 = rowsq[pj * 128 + wn * 32 + 16 + mrow] * c4;

        float4v acc[4][2];
        #pragma unroll
        for (int mt = 0; mt < 4; ++mt)
            #pragma unroll
            for (int nt = 0; nt < 2; ++nt)
                acc[mt][nt] = (float4v){0.f, 0.f, 0.f, 0.f};

        const uint4* As = Alds;
        const uint4* Bs = Blds[cur];
        #pragma unroll
        for (int kc = 0; kc < 4; ++kc) {
            short8 af[4], bf[2];
            #pragma unroll
            for (int mt = 0; mt < 4; ++mt)
                af[mt] = *(const short8*)&As[(wm * 4 + mt) * 256 + kc * 64 + lane];
            bf[0] = *(const short8*)&Bs[(wn * 2 + 0) * 256 + kc * 64 + lane];
            bf[1] = *(const short8*)&Bs[(wn * 2 + 1) * 256 + kc * 64 + lane];
            #pragma unroll
            for (int mt = 0; mt < 4; ++mt)
                #pragma unroll
                for (int nt = 0; nt < 2; ++nt)
                    acc[mt][nt] = __builtin_amdgcn_mfma_f32_16x16x32_bf16(af[mt], bf[nt], acc[mt][nt], 0, 0, 0);
        }

        // epilogue: e = exp2(pk_fma(d, -2c4, rA*c4 + rB*c4)); sum e^{1,2,4,8,16}
        float2v part2 = {0.f, 0.f};
        #pragma unroll
        for (int mt = 0; mt < 4; ++mt) {
            const float2v rA01 = {rAc[mt][0], rAc[mt][1]};
            const float2v rA23 = {rAc[mt][2], rAc[mt][3]};
            #pragma unroll
            for (int nt = 0; nt < 2; ++nt) {
                const float rB = nt ? rBc1 : rBc0;
                const float2v rB2 = {rB, rB};
                float4v d = acc[mt][nt];
                float2v d01 = {d[0], d[1]}, d23 = {d[2], d[3]};
                float2v a01 = d01 * cm2v + (rA01 + rB2);   // v_pk_fma + v_pk_add
                float2v a23 = d23 * cm2v + (rA23 + rB2);
                float2v e1a = { __builtin_amdgcn_exp2f(a01[0]), __builtin_amdgcn_exp2f(a01[1]) };
                float2v e1b = { __builtin_amdgcn_exp2f(a23[0]), __builtin_amdgcn_exp2f(a23[1]) };
                float2v e2a = e1a * e1a, e4a = e2a * e2a, e8a = e4a * e4a, e16a = e8a * e8a;
                float2v e2b = e1b * e1b, e4b = e2b * e2b, e8b = e4b * e4b, e16b = e8b * e8b;
                part2 += (e1a + e2a) + ((e4a + e8a) + e16a);
                part2 += (e1b + e2b) + ((e4b + e8b) + e16b);
            }
        }
        float part = part2[0] + part2[1];
        #pragma unroll
        for (int off = 32; off; off >>= 1) part += __shfl_down(part, off);

        if (lane == 0) {
            float wgt;
            if (pi == pj) {
                int wn64 = wn >> 1;
                if (wm == 1 && wn64 == 0) wgt = 0.f;          // duplicate quadrant
                else wgt = (wm == wn64) ? 1.f : 2.f;          // 64-diag vs off
            } else {
                wgt = ((pi < 32) == (pj < 32)) ? 2.f : -2.f;
            }
            wacc += (double)(wgt * part);
        }

        ++t; pj = npj; pi = npi;
        if (pre) cur ^= 1;
    }

    // block-level f64 reduce -> one non-returning atomic (8 adds per slot)
    __syncthreads();
    if (lane == 0) dred[wv] = wacc;
    __syncthreads();
    if (tid == 0) {
        double bs = ((dred[0] + dred[1]) + (dred[2] + dred[3])) +
                    ((dred[4] + dred[5]) + (dred[6] + dred[7]));
        atomicAdd((double*)(wsf + 192) + (b & 31), bs);   // fire-and-forget
    }
}

// ---- F: one wave reduces the 32 f64 slots ----
__global__ __launch_bounds__(64) void f_final(const float* __restrict__ wsf,
                                              float* __restrict__ out) {
    const int lane = threadIdx.x;
    const double* a = (const double*)(wsf + 192);
    double v = (lane < 32) ? a[lane] : 0.0;
    #pragma unroll
    for (int off = 32; off; off >>= 1) v += __shfl_down(v, off);
    if (lane == 0) out[0] = (float)(v * (1.0 / (4096.0 * 4096.0)));
}

extern "C" void kernel_launch(void* const* d_in, const int* in_sizes, int n_in,
                              void* d_out, int out_size, void* d_ws, size_t ws_size,
                              hipStream_t stream) {
    const float* src = (const float*)d_in[0];
    const float* tgt = (const float*)d_in[1];
    float* wsf = (float*)d_ws;
    unsigned int* XTu = (unsigned int*)(wsf + 65536);   // byte 256K, 2 MB tiled bf16

    hipMemsetAsync(wsf, 0, 1024, stream);   // ss32 + colsum + acc32
    hipLaunchKernelGGL(k_prep, dim3(2176), dim3(256), 0, stream, src, tgt, wsf, XTu);
    hipLaunchKernelGGL(mmd_main, dim3(MBLK), dim3(512), 0, stream,
                       (const uint4*)XTu, wsf);
    hipLaunchKernelGGL(f_final, dim3(1), dim3(64), 0, stream, wsf, (float*)d_out);
}